// Round 14
// baseline (110.212 us; speedup 1.0000x reference)
//
#include <hip/hip_runtime.h>
#include <hip/hip_bf16.h>

#define BATCH 16
#define SEQ 2048
#define DIM 64

typedef __attribute__((ext_vector_type(8))) __bf16 bf16x8;
typedef __attribute__((ext_vector_type(8))) unsigned short u16x8;
typedef __attribute__((ext_vector_type(4))) unsigned int u32x4;
typedef __attribute__((ext_vector_type(16))) float f32x16;

#if __has_builtin(__builtin_amdgcn_exp2f)
#define EXP2F(x) __builtin_amdgcn_exp2f(x)
#else
#define EXP2F(x) __expf(0.69314718055994531f * (x))
#endif

__device__ __forceinline__ unsigned short f2bf_hw(float f) {
    __bf16 h = (__bf16)f;
    return __builtin_bit_cast(unsigned short, h);
}

__device__ __forceinline__ unsigned int pk_bf16(float lo, float hi) {
    unsigned int a = f2bf_hw(lo), b = f2bf_hw(hi);
    return a | (b << 16);
}

__device__ __forceinline__ bf16x8 ld_bf8_g(const unsigned short* p) {
    u16x8 u = *(const u16x8*)p;
    return __builtin_bit_cast(bf16x8, u);
}

// Preconvert K and V to bf16 in fragment-order tile layout (unchanged).
// K slot s within each 32-key subtile stores the physical key with bits 2<->3
// of (s&31) swapped: S^T C-registers [8c2..8c2+7] then ARE the PV B-fragment
// in register order (no cross-lane swap). V natural order.
__global__ __launch_bounds__(256)
void preconvert_kv(const float* __restrict__ K, const float* __restrict__ V,
                   unsigned short* __restrict__ Ks, unsigned short* __restrict__ Vts) {
    const int tid = threadIdx.x;
    if (blockIdx.x < 256) {
        const int b = blockIdx.x >> 4;
        const int t = blockIdx.x & 15;
        const float* src = K + ((size_t)(b * SEQ + t * 128)) * DIM;
        unsigned short* dst = Ks + ((size_t)(b * 16 + t)) * 8192;
        #pragma unroll
        for (int p = 0; p < 4; ++p) {
            const int cid = p * 256 + tid;          // cid = slot*8 + g
            const int slot = cid >> 3, g = cid & 7;
            const int s32 = slot & 31;
            const int skey = (slot & ~31) | (s32 & ~12) | (((s32 >> 2) & 1) << 3) | (((s32 >> 3) & 1) << 2);
            const int d0 = (g >> 1) * 16 + (g & 1) * 8;
            float4 x0 = *(const float4*)(src + skey * DIM + d0);
            float4 x1 = *(const float4*)(src + skey * DIM + d0 + 4);
            u16x8 o;
            o[0] = f2bf_hw(x0.x); o[1] = f2bf_hw(x0.y); o[2] = f2bf_hw(x0.z); o[3] = f2bf_hw(x0.w);
            o[4] = f2bf_hw(x1.x); o[5] = f2bf_hw(x1.y); o[6] = f2bf_hw(x1.z); o[7] = f2bf_hw(x1.w);
            *(u16x8*)(dst + (g * 128 + slot) * 8) = o;
        }
    } else {
        const int vb = blockIdx.x - 256;
        const int b = vb >> 4;
        const int t = vb & 15;
        const float* src = V + ((size_t)(b * SEQ + t * 128)) * DIM;
        unsigned short* dst = Vts + ((size_t)(b * 16 + t)) * 8192;
        #pragma unroll
        for (int p = 0; p < 4; ++p) {
            const int cid = p * 256 + tid;          // cid = g*64 + d
            const int g = cid >> 6, d = cid & 63;
            const int k0 = (g >> 1) * 16 + (g & 1) * 8;
            u16x8 o;
            #pragma unroll
            for (int j = 0; j < 8; ++j) o[j] = f2bf_hw(src[(k0 + j) * DIM + d]);
            *(u16x8*)(dst + (g * 64 + d) * 8) = o;
        }
    }
}

// Main: no LDS staging, no main-loop barriers/cross-lane ops. Block = 64
// q-rows as 2 q-tiles x 2 KEY-HALVES: wave pairs (w0,w1)/(w2,w3) walk the SAME
// K/V subtile sequence in lockstep -> each stream is fetched once and L1-hit
// by the sibling (R13 had 4 disjoint quarter-streams/block thrashing L1).
// 1 q-set/wave, 32 iters of 32-key subtiles, depth-2 register ping-pong
// (reload in place for st+2). 2-way split-K combine through 17 KB LDS.
__global__ __launch_bounds__(256, 2)
void attn_flash_kernel(const float* __restrict__ Q,
                       const unsigned short* __restrict__ Ks,
                       const unsigned short* __restrict__ Vts,
                       const float* __restrict__ scaling,
                       float* __restrict__ O) {
    __shared__ float comb[2 * 64 * 33];   // 16,896 B

    const int tid  = threadIdx.x;
    const int w    = tid >> 6;
    const int qt   = w & 1;         // q-tile within block
    const int kw   = w >> 1;        // key half
    const int lane = tid & 63;
    const int m    = lane & 31;     // q-index within frags
    const int h    = lane >> 5;     // k-half selector

    // XCD-aware swizzle: 2 batches per XCD -> ~2 MB working set per 4 MB L2
    const int x  = blockIdx.x;
    const int b  = ((x & 7) << 1) | ((x >> 3) & 1);
    const int q0 = (x >> 4) * 64 + qt * 32;

    const float csc = 1.4426950408889634f / scaling[0];  // log2(e)/sqrt(D)

    // Q fragments, B-layout: lane (m,h) holds Q[q0+m][c*16+h*8+{0..7}] * csc
    bf16x8 aq[4];
    {
        const float* qsrc = Q + ((size_t)(b * SEQ + q0 + m)) * DIM + h * 8;
        #pragma unroll
        for (int c = 0; c < 4; ++c) {
            float4 x0 = *(const float4*)(qsrc + c * 16);
            float4 x1 = *(const float4*)(qsrc + c * 16 + 4);
            u32x4 pk;
            pk[0] = pk_bf16(x0.x * csc, x0.y * csc);
            pk[1] = pk_bf16(x0.z * csc, x0.w * csc);
            pk[2] = pk_bf16(x1.x * csc, x1.y * csc);
            pk[3] = pk_bf16(x1.z * csc, x1.w * csc);
            aq[c] = __builtin_bit_cast(bf16x8, pk);
        }
    }

    f32x16 Oacc[2];
    #pragma unroll
    for (int dt = 0; dt < 2; ++dt)
        #pragma unroll
        for (int r = 0; r < 16; ++r) Oacc[dt][r] = 0.f;
    float psum = 0.f;

    const unsigned short* Kbase = Ks + ((size_t)(b * 16 + kw * 8)) * 8192;
    const unsigned short* Vbase = Vts + ((size_t)(b * 16 + kw * 8)) * 8192;

    // prologue: fill both ping-pong buffers (subtiles 0 and 1 of tile 0)
    bf16x8 kb[2][4], vb[2][2][2];
    #pragma unroll
    for (int s = 0; s < 2; ++s) {
        #pragma unroll
        for (int c = 0; c < 4; ++c)
            kb[s][c] = ld_bf8_g(&Kbase[((c * 2 + h) * 128 + s * 32 + m) * 8]);
        #pragma unroll
        for (int c2 = 0; c2 < 2; ++c2)
            #pragma unroll
            for (int dt = 0; dt < 2; ++dt)
                vb[s][c2][dt] = ld_bf8_g(&Vbase[(((2 * s + c2) * 2 + h) * 64 + dt * 32 + m) * 8]);
    }

    #pragma unroll 2
    for (int st = 0; st < 32; ++st) {
        const int p = st & 1;   // compile-time under unroll 2

        // S^T = K Q^T
        f32x16 S;
        #pragma unroll
        for (int r = 0; r < 16; ++r) S[r] = 0.f;
        #pragma unroll
        for (int c = 0; c < 4; ++c)
            S = __builtin_amdgcn_mfma_f32_32x32x16_bf16(kb[p][c], aq[c], S, 0, 0, 0);

        // reload kb[p] in place for subtile st+2
        const int stn = (st + 2 < 32) ? st + 2 : 31;
        {
            const unsigned short* Ktn = Kbase + (size_t)(stn >> 2) * 8192;
            const int tn = stn & 3;
            #pragma unroll
            for (int c = 0; c < 4; ++c)
                kb[p][c] = ld_bf8_g(&Ktn[((c * 2 + h) * 128 + tn * 32 + m) * 8]);
        }

        // P = exp2(S); consecutive C-regs pack straight into the PV B-fragment
        #pragma unroll
        for (int c2 = 0; c2 < 2; ++c2) {
            u32x4 pw;
            #pragma unroll
            for (int i = 0; i < 4; ++i) {
                float a0 = EXP2F(S[8 * c2 + 2 * i + 0]);
                float a1 = EXP2F(S[8 * c2 + 2 * i + 1]);
                psum += a0 + a1;
                pw[i] = pk_bf16(a0, a1);
            }
            bf16x8 pb = __builtin_bit_cast(bf16x8, pw);
            #pragma unroll
            for (int dt = 0; dt < 2; ++dt)
                Oacc[dt] = __builtin_amdgcn_mfma_f32_32x32x16_bf16(vb[p][c2][dt], pb, Oacc[dt], 0, 0, 0);
        }

        // reload vb[p] in place for subtile st+2
        {
            const unsigned short* Vtn = Vbase + (size_t)(stn >> 2) * 8192;
            const int tn = stn & 3;
            #pragma unroll
            for (int c2 = 0; c2 < 2; ++c2)
                #pragma unroll
                for (int dt = 0; dt < 2; ++dt)
                    vb[p][c2][dt] = ld_bf8_g(&Vtn[(((2 * tn + c2) * 2 + h) * 64 + dt * 32 + m) * 8]);
        }
    }

    // combine the two key-halves through LDS, normalize, store
    float l = psum + __shfl_xor(psum, 32);
    if (kw == 1) {
        float* dst = comb + (qt * 64 + lane) * 33;
        #pragma unroll
        for (int dt = 0; dt < 2; ++dt)
            #pragma unroll
            for (int r = 0; r < 16; ++r) dst[dt * 16 + r] = Oacc[dt][r];
        dst[32] = l;
    }
    __syncthreads();
    if (kw == 0) {
        const float* pr = comb + (qt * 64 + lane) * 33;
        const float invl = 1.0f / (l + pr[32]);
        float* orow = O + ((size_t)(b * SEQ + q0 + m)) * DIM;
        #pragma unroll
        for (int dt = 0; dt < 2; ++dt) {
            #pragma unroll
            for (int k = 0; k < 4; ++k) {
                float4 o4;
                #pragma unroll
                for (int j = 0; j < 4; ++j) {
                    const int r = 4 * k + j;
                    ((float*)&o4)[j] = (Oacc[dt][r] + pr[dt * 16 + r]) * invl;
                }
                *(float4*)(orow + dt * 32 + 8 * k + 4 * h) = o4;
            }
        }
    }
}

extern "C" void kernel_launch(void* const* d_in, const int* in_sizes, int n_in,
                              void* d_out, int out_size, void* d_ws, size_t ws_size,
                              hipStream_t stream) {
    const float* Q = (const float*)d_in[0];
    const float* K = (const float*)d_in[1];
    const float* V = (const float*)d_in[2];
    const float* scaling = (const float*)d_in[3];
    float* O = (float*)d_out;

    unsigned short* Ks  = (unsigned short*)d_ws;                  // 4 MB
    unsigned short* Vts = Ks + (size_t)BATCH * 16 * 8192;         // 4 MB

    preconvert_kv<<<dim3(512), dim3(256), 0, stream>>>(K, V, Ks, Vts);
    attn_flash_kernel<<<dim3(BATCH * (SEQ / 64)), dim3(256), 0, stream>>>(Q, Ks, Vts, scaling, O);
}